// Round 18
// baseline (266.801 us; speedup 1.0000x reference)
//
#include <hip/hip_runtime.h>
#include <hip/hip_bf16.h>

#define SEQL 4096
#define DCH  1024
#define BATCH 4
#define KH   4097        // stored half-spectrum entries per channel

// packed complex: one VGPR pair
typedef __attribute__((ext_vector_type(2))) float cf;
__device__ __forceinline__ cf mkc(float x, float y){ cf r; r.x = x; r.y = y; return r; }
__device__ __forceinline__ cf cadd(cf a, cf b){ return a + b; }
__device__ __forceinline__ cf csub(cf a, cf b){ return a - b; }
__device__ __forceinline__ cf cmul(cf a, cf b){ return a.xx * b + mkc(-a.y, a.y) * b.yx; }
__device__ __forceinline__ cf cconjf(cf a){ return mkc(a.x, -a.y); }
__device__ __forceinline__ cf addi(cf a, cf b){ return a + mkc(-b.y, b.x); }  // a + i*b
__device__ __forceinline__ cf subi(cf a, cf b){ return a - mkc(-b.y, b.x); }  // a - i*b
// LDS index swizzle: XOR high nibble into low nibble (bijective; replaces +1/16 pad)
__device__ __forceinline__ int phi(int c){ return c ^ ((c >> 4) & 15); }
__device__ __forceinline__ int drev(int i){                                          // reverse 6 base-4 digits
    return ((i>>10)&3) | (((i>>8)&3)<<2) | (((i>>6)&3)<<4)
         | (((i>>4)&3)<<6) | (((i>>2)&3)<<8) | ((i&3)<<10);
}

// register-stage twiddles (compile-time constants)
__device__ __forceinline__ cf W1c(int j){   // e^{-2*pi*i*j/16}
    const float cs[4] = {1.f, 0.92387953f, 0.70710678f, 0.38268343f};
    const float sn[4] = {0.f, -0.38268343f, -0.70710678f, -0.92387953f};
    return mkc(cs[j], sn[j]);
}
__device__ __forceinline__ cf W2c(int j){   // e^{-2*pi*i*j/8}
    const float cs[4] = {1.f, 0.70710678f, 0.f, -0.70710678f};
    const float sn[4] = {0.f, -0.70710678f, -1.f, -0.70710678f};
    return mkc(cs[j], sn[j]);
}
__device__ __forceinline__ cf W3c(int j){   // e^{-2*pi*i*3j/16}
    const float cs[4] = {1.f, 0.38268343f, -0.70710678f, -0.92387953f};
    const float sn[4] = {0.f, -0.92387953f, -0.70710678f, 0.38268343f};
    return mkc(cs[j], sn[j]);
}

__device__ __forceinline__ unsigned pack2bf(float a, float b){
    unsigned r;
    asm("v_cvt_pk_bf16_f32 %0, %1, %2" : "=v"(r) : "v"(a), "v"(b));
    return r;   // lo = bf16(a), hi = bf16(b)
}
__device__ __forceinline__ float bflo(unsigned u){ return __uint_as_float(u << 16); }
__device__ __forceinline__ float bfhi(unsigned u){ return __uint_as_float(u & 0xffff0000u); }

__device__ __forceinline__ void gload16(const void* g, void* l){
    __builtin_amdgcn_global_load_lds((const __attribute__((address_space(1))) void*)g,
                                     (__attribute__((address_space(3))) void*)l, 16, 0, 0);
}

// ---------------- fused prologue: twiddles (blocks 0-15), MLP (16-31), pw->bf16 (32-543) ----------------
__global__ __launch_bounds__(256) void prep_kernel(
        cf* __restrict__ tw4, cf* __restrict__ tw8,
        const float* __restrict__ z, const float* __restrict__ w1,
        const float* __restrict__ b1, float* __restrict__ h,
        const float* __restrict__ pw, unsigned short* __restrict__ pwb) {
    const int blk = blockIdx.x;
    if (blk < 16) {
        int i = blk * 256 + threadIdx.x;   // 4096 total
        const double TWO_PI = 6.283185307179586476925286766559;
        double a4 = -TWO_PI * (double)i / 4096.0;
        double a8 = -TWO_PI * (double)i / 8192.0;
        tw4[i] = mkc((float)cos(a4), (float)sin(a4));
        tw8[i] = mkc((float)cos(a8), (float)sin(a8));
    } else if (blk < 32) {
        int l = (blk - 16) * 256 + threadIdx.x;
        float pe0 = z[l * 3 + 0], pe1 = z[l * 3 + 1], pe2 = z[l * 3 + 2];
#pragma unroll
        for (int j = 0; j < 16; ++j) {
            float v = pe0 * w1[j * 3 + 0] + pe1 * w1[j * 3 + 1] + pe2 * w1[j * 3 + 2] + b1[j];
            h[l * 16 + j] = v > 0.f ? v : 0.f;
        }
    } else if (pwb) {
        int t = (blk - 32) * 256 + threadIdx.x;
        float4 a = *(const float4*)&pw[(size_t)t * 8];
        float4 b = *(const float4*)&pw[(size_t)t * 8 + 4];
        uint4 o;
        o.x = pack2bf(a.x, a.y); o.y = pack2bf(a.z, a.w);
        o.z = pack2bf(b.x, b.y); o.w = pack2bf(b.z, b.w);
        *(uint4*)&pwb[(size_t)t * 8] = o;
    }
}

// ---- shared middle DIF passes (m=256,64,16), fwd chunk pass (m=4,m=1) ----
__device__ void dif_mid_and_chunk(cf* lds, const cf* __restrict__ tw){
    const int tid = threadIdx.x;
#pragma unroll
    for (int p = 1; p < 4; ++p) {
        const int lm = 10 - 2*p;          // 8,6,4
        const int m  = 1 << lm;
        const int step = 1024 >> lm;
#pragma unroll
        for (int it = 0; it < 4; ++it) {
            int j = tid + (it << 8);
            int k = j & (m-1);
            int g = j >> lm;
            int i0 = (g << (lm+2)) + k;
            cf x0 = lds[phi(i0)];
            cf x1 = lds[phi(i0+m)];
            cf x2 = lds[phi(i0+2*m)];
            cf x3 = lds[phi(i0+3*m)];
            cf b0 = cadd(x0,x2), b1 = csub(x0,x2);
            cf b2 = cadd(x1,x3), b3 = csub(x1,x3);
            cf u0 = cadd(b0,b2);
            cf u2 = csub(b0,b2);
            cf u1 = subi(b1,b3);
            cf u3 = addi(b1,b3);
            int t1 = k*step;
            lds[phi(i0)]     = u0;
            lds[phi(i0+m)]   = cmul(u1, tw[t1]);
            lds[phi(i0+2*m)] = cmul(u2, tw[2*t1]);
            lds[phi(i0+3*m)] = cmul(u3, tw[3*t1]);
        }
        __syncthreads();
    }
    {   // fused m=4 / m=1 register pass; thread owns complexes [16t,16t+16)
        const int b0 = tid << 4;
        const int xr = tid & 15;
        cf v[16];
#pragma unroll
        for (int j=0;j<16;++j) v[j] = lds[b0 + (j ^ xr)];
#pragma unroll
        for (int j=0;j<4;++j){
            cf x0=v[j], x1=v[j+4], x2=v[j+8], x3=v[j+12];
            cf b0v=cadd(x0,x2), b1=csub(x0,x2), b2=cadd(x1,x3), b3=csub(x1,x3);
            cf u0=cadd(b0v,b2), u2=csub(b0v,b2), u1=subi(b1,b3), u3=addi(b1,b3);
            v[j]    = u0;
            v[j+4]  = cmul(u1, W1c(j));
            v[j+8]  = cmul(u2, W2c(j));
            v[j+12] = cmul(u3, W3c(j));
        }
#pragma unroll
        for (int c=0;c<4;++c){
            cf x0=v[4*c], x1=v[4*c+1], x2=v[4*c+2], x3=v[4*c+3];
            cf b0v=cadd(x0,x2), b1=csub(x0,x2), b2=cadd(x1,x3), b3=csub(x1,x3);
            v[4*c]   = cadd(b0v,b2);
            v[4*c+1] = subi(b1,b3);
            v[4*c+2] = csub(b0v,b2);
            v[4*c+3] = addi(b1,b3);
        }
#pragma unroll
        for (int j=0;j<16;++j) lds[b0 + (j ^ xr)] = v[j];
        __syncthreads();
    }
}

// ---- inverse: chunk pass (m=1,m=4) + middle DIT passes (m=16,64,256) ----
__device__ void dit_chunk_and_mid(cf* lds, const cf* __restrict__ tw){
    const int tid = threadIdx.x;
    {
        const int b0 = tid << 4;
        const int xr = tid & 15;
        cf v[16];
#pragma unroll
        for (int j=0;j<16;++j) v[j] = lds[b0 + (j ^ xr)];
#pragma unroll
        for (int c=0;c<4;++c){
            cf a0=v[4*c], a1=v[4*c+1], a2=v[4*c+2], a3=v[4*c+3];
            cf b0v=cadd(a0,a2), b1=csub(a0,a2), b2=cadd(a1,a3), b3=csub(a1,a3);
            v[4*c]   = cadd(b0v,b2);
            v[4*c+1] = addi(b1,b3);
            v[4*c+2] = csub(b0v,b2);
            v[4*c+3] = subi(b1,b3);
        }
#pragma unroll
        for (int j=0;j<4;++j){
            cf a0=v[j];
            cf a1=cmul(v[j+4],  cconjf(W1c(j)));
            cf a2=cmul(v[j+8],  cconjf(W2c(j)));
            cf a3=cmul(v[j+12], cconjf(W3c(j)));
            cf b0v=cadd(a0,a2), b1=csub(a0,a2), b2=cadd(a1,a3), b3=csub(a1,a3);
            v[j]    = cadd(b0v,b2);
            v[j+4]  = addi(b1,b3);
            v[j+8]  = csub(b0v,b2);
            v[j+12] = subi(b1,b3);
        }
#pragma unroll
        for (int j=0;j<16;++j) lds[b0 + (j ^ xr)] = v[j];
        __syncthreads();
    }
#pragma unroll
    for (int p = 0; p < 3; ++p) {
        const int lm = 4 + 2*p;           // 16,64,256
        const int m  = 1 << lm;
        const int step = 1024 >> lm;
#pragma unroll
        for (int it = 0; it < 4; ++it) {
            int j = tid + (it << 8);
            int k = j & (m-1);
            int g = j >> lm;
            int i0 = (g << (lm+2)) + k;
            int t1 = k*step;
            cf a0 = lds[phi(i0)];
            cf a1 = cmul(lds[phi(i0+m)],   cconjf(tw[t1]));
            cf a2 = cmul(lds[phi(i0+2*m)], cconjf(tw[2*t1]));
            cf a3 = cmul(lds[phi(i0+3*m)], cconjf(tw[3*t1]));
            cf b0=cadd(a0,a2), b1=csub(a0,a2), b2=cadd(a1,a3), b3=csub(a1,a3);
            lds[phi(i0)]     = cadd(b0,b2);
            lds[phi(i0+m)]   = addi(b1,b3);
            lds[phi(i0+2*m)] = csub(b0,b2);
            lds[phi(i0+3*m)] = subi(b1,b3);
        }
        __syncthreads();
    }
}

// ---------------- fused transpose + filter-FFT: independent work, one dispatch ----------------
// grid = 1024*17; r = g%17: r==0 -> filt block d=g/17; else transpose block t=16*(g/17)+r-1.
// The 1:16 interleave keeps VALU-bound filt blocks co-resident with BW-bound transpose
// blocks on every CU, overlapping the two phases.
__global__ __launch_bounds__(256) void tf_kernel(
        const float* __restrict__ u, unsigned* __restrict__ utb,
        unsigned short* __restrict__ ub,
        const float* __restrict__ h, const float* __restrict__ w2,
        const float* __restrict__ b2, const cf* __restrict__ tw4,
        const cf* __restrict__ tw8, cf* __restrict__ kf) {
    __shared__ cf lds[4096];
    const int g = blockIdx.x;
    const int q = g / 17;
    const int r = g - q * 17;
    const int tid = threadIdx.x;
    if (r != 0) {
        // ---- transpose tile t ----
        float (*tile)[33] = (float(*)[33])lds;
        const int t  = q * 16 + (r - 1);
        const int b  = t >> 12;
        const int d0 = ((t >> 7) & 31) << 5;
        const int l0 = (t & 127) << 5;
        const int tx = tid & 31, ty = tid >> 5;    // 32 x 8
        const float* up = u + (size_t)b * SEQL * DCH;
        unsigned short* ubp = ub ? ub + (size_t)b * SEQL * DCH : (unsigned short*)0;
#pragma unroll
        for (int i = 0; i < 32; i += 8) {
            size_t idx = (size_t)(l0 + ty + i) * DCH + d0 + tx;
            float v = up[idx];
            tile[ty + i][tx] = v;
            if (ub) ubp[idx] = (unsigned short)pack2bf(v, v);
        }
        __syncthreads();
        unsigned* utp = utb + (size_t)b * DCH * (SEQL / 2);
        int dl = tid >> 4;              // 0..15
        int lp = tid & 15;              // l-pair index
#pragma unroll
        for (int p = 0; p < 2; ++p) {
            int dd = dl + p * 16;
            unsigned v = pack2bf(tile[2 * lp][dd], tile[2 * lp + 1][dd]);
            utp[(size_t)(d0 + dd) * (SEQL / 2) + (l0 >> 1) + lp] = v;
        }
        return;
    }
    // ---- filter FFT, channel d = q ----
    const int d = q;
    float wv[16];
#pragma unroll
    for (int j = 0; j < 16; ++j) wv[j] = w2[d * 16 + j];
    const float bb = b2[d];
#pragma unroll
    for (int it = 0; it < 4; ++it) {
        int j = tid + (it << 8);
        const float* h0 = h + (size_t)(2*j) * 16;
        const float* h1 = h + (size_t)(2*(j+1024)) * 16;
        float f0 = bb, f1 = bb, f2 = bb, f3 = bb;
#pragma unroll
        for (int i = 0; i < 16; ++i) {
            f0 += h0[i] * wv[i];  f1 += h0[16+i] * wv[i];
            f2 += h1[i] * wv[i];  f3 += h1[16+i] * wv[i];
        }
        cf x0 = mkc(f0, f1), x1 = mkc(f2, f3);
        cf u0 = cadd(x0,x1);
        cf u2 = csub(x0,x1);
        cf u1 = subi(x0,x1);
        cf u3 = addi(x0,x1);
        lds[phi(j)]      = u0;
        lds[phi(j+1024)] = cmul(u1, tw4[j]);
        lds[phi(j+2048)] = cmul(u2, tw4[2*j]);
        lds[phi(j+3072)] = cmul(u3, tw4[3*j]);
    }
    __syncthreads();
    dif_mid_and_chunk(lds, tw4);
    const float s = 1.f / 8192.f;
    cf* Hrow = kf + (size_t)d * KH;
    const int lane  = tid & 63;
    const int kbase = ((lane & 31) << 6) | ((lane >> 5) << 5) | ((tid >> 6) << 3);
#pragma unroll
    for (int it = 0; it < 8; ++it) {
        int k = kbase + it;
        if (k == 0) {
            cf c0 = lds[0];
            Hrow[0]    = mkc((c0.x + c0.y) * s, 0.f);
            Hrow[4096] = mkc((c0.x - c0.y) * s, 0.f);
            cf c2 = lds[phi(drev(2048))];
            Hrow[2048] = mkc(c2.x * s, -c2.y * s);
        } else {
            int kk = 4096 - k;
            cf ck  = lds[phi(drev(k))];
            cf ckk = lds[phi(drev(kk))];
            cf cc = cconjf(ckk);
            cf E  = (ck + cc) * 0.5f;
            cf Dd = csub(ck, cc);
            cf O  = mkc(Dd.y, -Dd.x) * 0.5f;
            cf wvv = tw8[k];
            cf Xk  = cadd(E, cmul(wvv, O));
            cf wp  = mkc(-wvv.x, wvv.y);
            cf Xkk = cadd(cconjf(E), cmul(wp, cconjf(O)));
            Hrow[k]  = Xk * s;
            Hrow[kk] = Xkk * s;
        }
    }
}

// ---------------- conv: bf16 in -> packed fwd FFT -> multiply -> inv FFT -> bf16 y (in place) ----------------
// grid swizzle: g = (d%8) + 8*b + 32*(d/8)  -> the 4 batch rows sharing H[d] map to the
// same XCD, turning repeat Hrow reads into same-XCD L2 hits.
__global__ __launch_bounds__(256) void conv_kernel(
        unsigned* __restrict__ utyb, const cf* __restrict__ tw4,
        const cf* __restrict__ tw8, const cf* __restrict__ kf) {
    __shared__ cf lds[4096];
    const int g   = blockIdx.x;
    const int d   = (g & 7) | ((g >> 5) << 3);
    const int b   = (g >> 3) & 3;
    const int row = b * DCH + d;
    const int tid = threadIdx.x;
    unsigned* rp = utyb + (size_t)row * (SEQL / 2);
#pragma unroll
    for (int it = 0; it < 4; ++it) {
        int j = tid + (it << 8);
        unsigned q0 = rp[j], q1 = rp[j + 1024];
        cf x0 = mkc(bflo(q0), bfhi(q0));
        cf x1 = mkc(bflo(q1), bfhi(q1));
        cf u0 = cadd(x0,x1);
        cf u2 = csub(x0,x1);
        cf u1 = subi(x0,x1);
        cf u3 = addi(x0,x1);
        lds[phi(j)]      = u0;
        lds[phi(j+1024)] = cmul(u1, tw4[j]);
        lds[phi(j+2048)] = cmul(u2, tw4[2*j]);
        lds[phi(j+3072)] = cmul(u3, tw4[3*j]);
    }
    __syncthreads();
    dif_mid_and_chunk(lds, tw4);
    const cf* Hrow = kf + (size_t)d * KH;
    {
        const int lane  = tid & 63;
        const int kbase = ((lane & 31) << 6) | ((lane >> 5) << 5) | ((tid >> 6) << 3);
#pragma unroll
        for (int it = 0; it < 8; ++it) {
            int k = kbase + it;
            if (k == 0) {
                cf c0 = lds[0];
                float X0 = c0.x + c0.y, X4 = c0.x - c0.y;
                cf H0 = Hrow[0], H4 = Hrow[4096];
                cf Y0 = H0 * X0;
                cf Y4 = H4 * X4;
                cf S  = cadd(Y0, Y4), Dd = csub(Y0, Y4);
                lds[0] = addi(S, Dd);
                int s2 = phi(drev(2048));
                cf c2 = lds[s2];
                cf Y2 = cmul(cconjf(c2), Hrow[2048]);
                lds[s2] = mkc(2.f * Y2.x, -2.f * Y2.y);
            } else {
                int kk = 4096 - k;
                int sk = phi(drev(k)), skk = phi(drev(kk));
                cf ck = lds[sk], ckk = lds[skk];
                cf cc = cconjf(ckk);
                cf E  = (ck + cc) * 0.5f;
                cf Dd = csub(ck, cc);
                cf O  = mkc(Dd.y, -Dd.x) * 0.5f;
                cf wv = tw8[k];
                cf Xk  = cadd(E, cmul(wv, O));
                cf wp  = mkc(-wv.x, wv.y);
                cf Xkk = cadd(cconjf(E), cmul(wp, cconjf(O)));
                cf Yk  = cmul(Xk,  Hrow[k]);
                cf Ykk = cmul(Xkk, Hrow[kk]);
                cf cy = cconjf(Ykk);
                cf S  = cadd(Yk, cy), D2 = csub(Yk, cy);
                cf Zk = addi(S, cmul(cconjf(wv), D2));
                cf cy2 = cconjf(Yk);
                cf S2  = cadd(Ykk, cy2), D3 = csub(Ykk, cy2);
                cf Zkk = subi(S2, cmul(wv, D3));
                lds[sk] = Zk; lds[skk] = Zkk;
            }
        }
    }
    __syncthreads();
    dit_chunk_and_mid(lds, tw4);
#pragma unroll
    for (int it = 0; it < 4; ++it) {
        int j = tid + (it << 8);
        cf a0 = lds[phi(j)];
        cf a1 = cmul(lds[phi(j+1024)], cconjf(tw4[j]));
        cf a2 = cmul(lds[phi(j+2048)], cconjf(tw4[2*j]));
        cf a3 = cmul(lds[phi(j+3072)], cconjf(tw4[3*j]));
        cf b0 = cadd(a0,a2), b1 = csub(a0,a2);
        cf b2 = cadd(a1,a3), b3 = csub(a1,a3);
        cf o0 = cadd(b0,b2);           // n = j
        cf o1 = addi(b1,b3);           // n = j+1024
        rp[j]        = pack2bf(o0.x, o0.y);
        rp[j + 1024] = pack2bf(o1.x, o1.y);
    }
}

typedef __attribute__((ext_vector_type(8))) short short8;
typedef __attribute__((ext_vector_type(4))) float f32x4;

// ---------------- gemm v3: 256x128 tile, BK=64, 3-buffer phase-split pipeline ----------------
__global__ __launch_bounds__(512, 2) void gemm_mfma_v3(
        const unsigned short* __restrict__ ub, const unsigned short* __restrict__ pwb,
        const float* __restrict__ pb, const unsigned short* __restrict__ yb,
        float* __restrict__ out) {
    __shared__ char lds_raw[147456];   // 3 bufs x (A 32K + B 16K); epilogue overlays [128][132] f32
    float (*ysc)[132] = (float(*)[132])lds_raw;

    const int tid  = threadIdx.x;
    const int lane = tid & 63;
    const int wid  = tid >> 6;          // 0..7
    const int wr   = wid >> 1;          // 0..3  (64 m-rows each)
    const int wc   = wid & 1;           // 0..1  (64 n-cols each)
    const int m0   = blockIdx.x * 256;
    const int n0   = blockIdx.y * 128;

    f32x4 acc[4][4] = {};

#pragma unroll
    for (int tt = 0; tt < 2; ++tt) {
#pragma unroll
        for (int un = 0; un < 3; ++un) {
            const unsigned short* gs = (un == 2) ? pwb : ub;
            int growb = (un == 2) ? n0 : (m0 + un * 128);
#pragma unroll
            for (int j = 0; j < 2; ++j) {
                int rr = j * 64 + (tid >> 3);
                int ss = (tid & 7) ^ ((tid >> 3) & 7);
                gload16(gs + (size_t)(growb + rr) * 1024 + tt * 64 + ss * 8,
                        lds_raw + tt * 49152 + un * 16384 + rr * 128 + (tid & 7) * 16);
            }
        }
    }
    asm volatile("s_waitcnt vmcnt(6)" ::: "memory");
    __builtin_amdgcn_sched_barrier(0);
    __builtin_amdgcn_s_barrier();

    for (int t = 0; t < 16; ++t) {
        const int Ab  = (t % 3) * 49152;
        const int Bb  = Ab + 32768;
        const int sbB = ((t + 2) % 3) * 49152;
        const int kt2 = (t + 2) * 64;
#pragma unroll
        for (int q = 0; q < 4; ++q) {
            const int qr = q >> 1, qc = q & 1;
            short8 af[2][2], bfr[2][2];
#pragma unroll
            for (int f = 0; f < 2; ++f) {
                int arow = wr * 64 + qr * 32 + f * 16 + (lane & 15);
                int brow = wc * 64 + qc * 32 + f * 16 + (lane & 15);
#pragma unroll
                for (int kh = 0; kh < 2; ++kh) {
                    int ks = (lane >> 4) + 4 * kh;
                    af[f][kh]  = *(short8*)(lds_raw + Ab + arow * 128 + (ks ^ (arow & 7)) * 16);
                    bfr[f][kh] = *(short8*)(lds_raw + Bb + brow * 128 + (ks ^ (brow & 7)) * 16);
                }
            }
            if (q < 3 && t < 14) {
                const unsigned short* gs = (q == 2) ? pwb : ub;
                int growb = (q == 2) ? n0 : (m0 + q * 128);
#pragma unroll
                for (int j = 0; j < 2; ++j) {
                    int rr = j * 64 + (tid >> 3);
                    int ss = (tid & 7) ^ ((tid >> 3) & 7);
                    gload16(gs + (size_t)(growb + rr) * 1024 + kt2 + ss * 8,
                            lds_raw + sbB + q * 16384 + rr * 128 + (tid & 7) * 16);
                }
            }
            __builtin_amdgcn_s_barrier();
            asm volatile("s_waitcnt lgkmcnt(0)" ::: "memory");
            __builtin_amdgcn_sched_barrier(0);
            __builtin_amdgcn_s_setprio(1);
#pragma unroll
            for (int fa = 0; fa < 2; ++fa)
#pragma unroll
                for (int fb = 0; fb < 2; ++fb)
#pragma unroll
                    for (int kh = 0; kh < 2; ++kh)
                        acc[qr * 2 + fa][qc * 2 + fb] = __builtin_amdgcn_mfma_f32_16x16x32_bf16(
                            af[fa][kh], bfr[fb][kh], acc[qr * 2 + fa][qc * 2 + fb], 0, 0, 0);
            __builtin_amdgcn_s_setprio(0);
            if (q == 3) {
                if (t < 14)       asm volatile("s_waitcnt vmcnt(6)" ::: "memory");
                else if (t == 14) asm volatile("s_waitcnt vmcnt(0)" ::: "memory");
                __builtin_amdgcn_sched_barrier(0);
            }
            __builtin_amdgcn_s_barrier();
        }
    }

    __syncthreads();
    const int b  = m0 >> 12;
    const int l0 = m0 & (SEQL - 1);
    float pbv[4];
#pragma unroll
    for (int nf = 0; nf < 4; ++nf)
        pbv[nf] = pb[n0 + wc * 64 + nf * 16 + (lane & 15)];

    for (int c = 0; c < 2; ++c) {
        __syncthreads();
        {
            int dn = tid >> 2;
            int lq = tid & 3;
            const uint4* uptr = (const uint4*)(yb + (((size_t)(b * DCH + n0 + dn)) << 12) + l0 + c * 128);
#pragma unroll
            for (int jj = 0; jj < 4; ++jj) {
                uint4 w4 = uptr[lq * 4 + jj];
                int lb = (lq * 4 + jj) * 8;
                ysc[lb+0][dn] = bflo(w4.x); ysc[lb+1][dn] = bfhi(w4.x);
                ysc[lb+2][dn] = bflo(w4.y); ysc[lb+3][dn] = bfhi(w4.y);
                ysc[lb+4][dn] = bflo(w4.z); ysc[lb+5][dn] = bfhi(w4.z);
                ysc[lb+6][dn] = bflo(w4.w); ysc[lb+7][dn] = bfhi(w4.w);
            }
        }
        __syncthreads();
        if ((wr >> 1) == c) {
#pragma unroll
            for (int mf = 0; mf < 4; ++mf)
#pragma unroll
                for (int i = 0; i < 4; ++i) {
                    int lrow = (wr & 1) * 64 + mf * 16 + (lane >> 4) * 4 + i;
                    int m = m0 + c * 128 + lrow;
#pragma unroll
                    for (int nf = 0; nf < 4; ++nf) {
                        int nl = wc * 64 + nf * 16 + (lane & 15);
                        int n = n0 + nl;
                        float proj = acc[mf][nf][i] + pbv[nf];
                        float ures = __uint_as_float((unsigned)ub[(size_t)m * DCH + n] << 16);
                        out[(size_t)m * DCH + n] = ysc[lrow][nl] * proj + ures;
                    }
                }
        }
    }
}

// ---------------- gemm fallback (reg-staged): used when ws too small ----------------
__global__ __launch_bounds__(256, 3) void gemm_mfma_fb(
        const float* __restrict__ u, const float* __restrict__ pw,
        const float* __restrict__ pb, const unsigned short* __restrict__ yb,
        float* __restrict__ out) {
    __shared__ char lds_raw[34816];
    float (*ysc)[132] = (float(*)[132])lds_raw;
    const int tid  = threadIdx.x;
    const int lane = tid & 63;
    const int wid  = tid >> 6;
    const int wr   = wid >> 1;
    const int wc   = wid & 1;
    const int m0   = blockIdx.x * 128;
    const int n0   = blockIdx.y * 128;
    f32x4 acc[4][4] = {};
    float4 ra[4], rb[4];
    int s_row[4], s_f4[4];
#pragma unroll
    for (int j = 0; j < 4; ++j) {
        int idx = j * 256 + tid;
        s_row[j] = idx >> 3;
        s_f4[j]  = idx & 7;
    }
#define LOADT(kt)                                                                     \
    {                                                                                 \
        _Pragma("unroll")                                                             \
        for (int j = 0; j < 4; ++j) {                                                 \
            ra[j] = *(const float4*)&u [(size_t)(m0 + s_row[j]) * DCH + (kt) + s_f4[j] * 4]; \
            rb[j] = *(const float4*)&pw[(size_t)(n0 + s_row[j]) * DCH + (kt) + s_f4[j] * 4]; \
        }                                                                             \
    }
#define WRITET(base)                                                                  \
    {                                                                                 \
        _Pragma("unroll")                                                             \
        for (int j = 0; j < 4; ++j) {                                                 \
            int off = (base) + ((s_row[j] * 64 + s_f4[j] * 8) ^ ((s_row[j] & 3) << 4)); \
            uint2 pa, pbv2;                                                           \
            pa.x   = pack2bf(ra[j].x, ra[j].y);  pa.y   = pack2bf(ra[j].z, ra[j].w);  \
            pbv2.x = pack2bf(rb[j].x, rb[j].y);  pbv2.y = pack2bf(rb[j].z, rb[j].w);  \
            *(uint2*)(lds_raw + off)        = pa;                                     \
            *(uint2*)(lds_raw + off + 8192) = pbv2;                                   \
        }                                                                             \
    }
    LOADT(0);
    WRITET(0);
    LOADT(32);
    __syncthreads();
    for (int t = 0; t < 32; ++t) {
        const int cur = (t & 1) << 14;
        short8 af[4], bfr[4];
#pragma unroll
        for (int f = 0; f < 4; ++f) {
            int rowA = wr * 64 + f * 16 + (lane & 15);
            int rowB = wc * 64 + f * 16 + (lane & 15);
            int offA = cur + ((rowA * 64 + ((lane >> 4) * 16)) ^ ((rowA & 3) << 4));
            int offB = cur + 8192 + ((rowB * 64 + ((lane >> 4) * 16)) ^ ((rowB & 3) << 4));
            af[f]  = *(short8*)(lds_raw + offA);
            bfr[f] = *(short8*)(lds_raw + offB);
        }
        if (t < 31) WRITET(cur ^ 16384);
        if (t < 30) LOADT((t + 2) * 32);
#pragma unroll
        for (int mf = 0; mf < 4; ++mf)
#pragma unroll
            for (int nf = 0; nf < 4; ++nf)
                acc[mf][nf] = __builtin_amdgcn_mfma_f32_16x16x32_bf16(
                    af[mf], bfr[nf], acc[mf][nf], 0, 0, 0);
        __syncthreads();
    }
    const int b  = m0 >> 12;
    const int l0 = m0 & (SEQL - 1);
    float pbv[4];
#pragma unroll
    for (int nf = 0; nf < 4; ++nf)
        pbv[nf] = pb[n0 + wc * 64 + nf * 16 + (lane & 15)];
    for (int c = 0; c < 2; ++c) {
        __syncthreads();
#pragma unroll
        for (int j = 0; j < 4; ++j) {
            int idx = j * 256 + tid;
            int dn  = idx >> 3;
            int lg  = idx & 7;
            uint4 w4 = *(const uint4*)&yb[(((size_t)(b * DCH + n0 + dn)) << 12) + l0 + c * 64 + lg * 8];
            int lb = lg * 8;
            ysc[lb+0][dn] = bflo(w4.x); ysc[lb+1][dn] = bfhi(w4.x);
            ysc[lb+2][dn] = bflo(w4.y); ysc[lb+3][dn] = bfhi(w4.y);
            ysc[lb+4][dn] = bflo(w4.z); ysc[lb+5][dn] = bfhi(w4.z);
            ysc[lb+6][dn] = bflo(w4.w); ysc[lb+7][dn] = bfhi(w4.w);
        }
        __syncthreads();
        if (wr == c) {
#pragma unroll
            for (int mf = 0; mf < 4; ++mf)
#pragma unroll
                for (int i = 0; i < 4; ++i) {
                    int lrow = mf * 16 + (lane >> 4) * 4 + i;
                    int m = m0 + c * 64 + lrow;
#pragma unroll
                    for (int nf = 0; nf < 4; ++nf) {
                        int nl = wc * 64 + nf * 16 + (lane & 15);
                        int n = n0 + nl;
                        float proj = acc[mf][nf][i] + pbv[nf];
                        out[(size_t)m * DCH + n] = ysc[lrow][nl] * proj + u[(size_t)m * DCH + n];
                    }
                }
        }
    }
#undef LOADT
#undef WRITET
}

extern "C" void kernel_launch(void* const* d_in, const int* in_sizes, int n_in,
                              void* d_out, int out_size, void* d_ws, size_t ws_size,
                              hipStream_t stream) {
    const float* u  = (const float*)d_in[0];
    const float* z  = (const float*)d_in[1];
    const float* w1 = (const float*)d_in[2];
    const float* b1 = (const float*)d_in[3];
    const float* w2 = (const float*)d_in[4];
    const float* b2 = (const float*)d_in[5];
    const float* pw = (const float*)d_in[6];
    const float* pb = (const float*)d_in[7];
    float* out = (float*)d_out;

    float*    h    = (float*)d_ws;                        // 256 KB
    unsigned* utyb = (unsigned*)((char*)d_ws + 262144);   // 32 MB (bf16-pair rows; y bf16 in place)
    cf* kf = (cf*)d_out;                                  // 33.5 MB scratch (overwritten by gemm)

    const size_t ub_off  = 262144 + (size_t)BATCH * DCH * (SEQL / 2) * sizeof(unsigned);
    const size_t pwb_off = ub_off + (size_t)BATCH * SEQL * DCH * sizeof(unsigned short);
    const size_t tw_off  = pwb_off + (size_t)DCH * DCH * sizeof(unsigned short);
    const size_t need    = tw_off + 2 * 4096 * sizeof(cf);
    const bool   big     = ws_size >= need;

    cf* tw4 = big ? (cf*)((char*)d_ws + tw_off) : (cf*)((char*)d_out + (40u << 20));
    cf* tw8 = tw4 + 4096;
    unsigned short* ub  = big ? (unsigned short*)((char*)d_ws + ub_off)  : (unsigned short*)0;
    unsigned short* pwb = big ? (unsigned short*)((char*)d_ws + pwb_off) : (unsigned short*)0;

    prep_kernel<<<dim3(big ? 544 : 32), dim3(256), 0, stream>>>(tw4, tw8, z, w1, b1, h, pw, pwb);
    tf_kernel<<<dim3(1024 * 17), dim3(256), 0, stream>>>(u, utyb, ub, h, w2, b2, tw4, tw8, kf);
    conv_kernel<<<dim3(BATCH * DCH), dim3(256), 0, stream>>>(utyb, tw4, tw8, kf);
    if (big)
        gemm_mfma_v3<<<dim3(64, 8), dim3(512), 0, stream>>>(ub, pwb, pb, (const unsigned short*)utyb, out);
    else
        gemm_mfma_fb<<<dim3(128, 8), dim3(256), 0, stream>>>(u, pw, pb, (const unsigned short*)utyb, out);
}

// Round 19
// 253.545 us; speedup vs baseline: 1.0523x; 1.0523x over previous
//
#include <hip/hip_runtime.h>
#include <hip/hip_bf16.h>

#define SEQL 4096
#define DCH  1024
#define BATCH 4
#define KH   4097        // stored half-spectrum entries per channel

// packed complex: one VGPR pair
typedef __attribute__((ext_vector_type(2))) float cf;
__device__ __forceinline__ cf mkc(float x, float y){ cf r; r.x = x; r.y = y; return r; }
__device__ __forceinline__ cf cadd(cf a, cf b){ return a + b; }
__device__ __forceinline__ cf csub(cf a, cf b){ return a - b; }
__device__ __forceinline__ cf cmul(cf a, cf b){ return a.xx * b + mkc(-a.y, a.y) * b.yx; }
__device__ __forceinline__ cf cconjf(cf a){ return mkc(a.x, -a.y); }
__device__ __forceinline__ cf addi(cf a, cf b){ return a + mkc(-b.y, b.x); }  // a + i*b
__device__ __forceinline__ cf subi(cf a, cf b){ return a - mkc(-b.y, b.x); }  // a - i*b
// LDS index swizzle: XOR high nibble into low nibble (bijective; replaces +1/16 pad)
__device__ __forceinline__ int phi(int c){ return c ^ ((c >> 4) & 15); }
__device__ __forceinline__ int drev(int i){                                          // reverse 6 base-4 digits
    return ((i>>10)&3) | (((i>>8)&3)<<2) | (((i>>6)&3)<<4)
         | (((i>>4)&3)<<6) | (((i>>2)&3)<<8) | ((i&3)<<10);
}

// register-stage twiddles (compile-time constants)
__device__ __forceinline__ cf W1c(int j){   // e^{-2*pi*i*j/16}
    const float cs[4] = {1.f, 0.92387953f, 0.70710678f, 0.38268343f};
    const float sn[4] = {0.f, -0.38268343f, -0.70710678f, -0.92387953f};
    return mkc(cs[j], sn[j]);
}
__device__ __forceinline__ cf W2c(int j){   // e^{-2*pi*i*j/8}
    const float cs[4] = {1.f, 0.70710678f, 0.f, -0.70710678f};
    const float sn[4] = {0.f, -0.70710678f, -1.f, -0.70710678f};
    return mkc(cs[j], sn[j]);
}
__device__ __forceinline__ cf W3c(int j){   // e^{-2*pi*i*3j/16}
    const float cs[4] = {1.f, 0.38268343f, -0.70710678f, -0.92387953f};
    const float sn[4] = {0.f, -0.92387953f, -0.70710678f, 0.38268343f};
    return mkc(cs[j], sn[j]);
}

__device__ __forceinline__ unsigned pack2bf(float a, float b){
    unsigned r;
    asm("v_cvt_pk_bf16_f32 %0, %1, %2" : "=v"(r) : "v"(a), "v"(b));
    return r;   // lo = bf16(a), hi = bf16(b)
}
__device__ __forceinline__ float bflo(unsigned u){ return __uint_as_float(u << 16); }
__device__ __forceinline__ float bfhi(unsigned u){ return __uint_as_float(u & 0xffff0000u); }

__device__ __forceinline__ void gload16(const void* g, void* l){
    __builtin_amdgcn_global_load_lds((const __attribute__((address_space(1))) void*)g,
                                     (__attribute__((address_space(3))) void*)l, 16, 0, 0);
}

// ---------------- fused prologue: twiddles (blocks 0-15), MLP (16-31), pw->bf16 (32-543) ----------------
__global__ __launch_bounds__(256) void prep_kernel(
        cf* __restrict__ tw4, cf* __restrict__ tw8,
        const float* __restrict__ z, const float* __restrict__ w1,
        const float* __restrict__ b1, float* __restrict__ h,
        const float* __restrict__ pw, unsigned short* __restrict__ pwb) {
    const int blk = blockIdx.x;
    if (blk < 16) {
        int i = blk * 256 + threadIdx.x;   // 4096 total
        const double TWO_PI = 6.283185307179586476925286766559;
        double a4 = -TWO_PI * (double)i / 4096.0;
        double a8 = -TWO_PI * (double)i / 8192.0;
        tw4[i] = mkc((float)cos(a4), (float)sin(a4));
        tw8[i] = mkc((float)cos(a8), (float)sin(a8));
    } else if (blk < 32) {
        int l = (blk - 16) * 256 + threadIdx.x;
        float pe0 = z[l * 3 + 0], pe1 = z[l * 3 + 1], pe2 = z[l * 3 + 2];
#pragma unroll
        for (int j = 0; j < 16; ++j) {
            float v = pe0 * w1[j * 3 + 0] + pe1 * w1[j * 3 + 1] + pe2 * w1[j * 3 + 2] + b1[j];
            h[l * 16 + j] = v > 0.f ? v : 0.f;
        }
    } else if (pwb) {
        int t = (blk - 32) * 256 + threadIdx.x;
        float4 a = *(const float4*)&pw[(size_t)t * 8];
        float4 b = *(const float4*)&pw[(size_t)t * 8 + 4];
        uint4 o;
        o.x = pack2bf(a.x, a.y); o.y = pack2bf(a.z, a.w);
        o.z = pack2bf(b.x, b.y); o.w = pack2bf(b.z, b.w);
        *(uint4*)&pwb[(size_t)t * 8] = o;
    }
}

// ---------------- transpose u (B,L,D) -> utb (B,D,L/2 uint of bf16 pairs) + ub = bf16(u) ----------------
__global__ __launch_bounds__(256) void transpose_kernel(
        const float* __restrict__ u, unsigned* __restrict__ utb,
        unsigned short* __restrict__ ub) {
    __shared__ float tile[32][33];
    int b = blockIdx.z;
    int l0 = blockIdx.x * 32;
    int d0 = blockIdx.y * 32;
    int tx = threadIdx.x, ty = threadIdx.y;  // 32 x 8
    const float* up = u + (size_t)b * SEQL * DCH;
    unsigned short* ubp = ub ? ub + (size_t)b * SEQL * DCH : (unsigned short*)0;
#pragma unroll
    for (int i = 0; i < 32; i += 8) {
        size_t idx = (size_t)(l0 + ty + i) * DCH + d0 + tx;
        float v = up[idx];
        tile[ty + i][tx] = v;
        if (ub) ubp[idx] = (unsigned short)pack2bf(v, v);
    }
    __syncthreads();
    unsigned* utp = utb + (size_t)b * DCH * (SEQL / 2);
    int t  = ty * 32 + tx;          // 0..255
    int dl = t >> 4;                // 0..15
    int lp = t & 15;                // l-pair index: l = 2lp, 2lp+1
#pragma unroll
    for (int p = 0; p < 2; ++p) {
        int dd = dl + p * 16;
        unsigned v = pack2bf(tile[2 * lp][dd], tile[2 * lp + 1][dd]);
        utp[(size_t)(d0 + dd) * (SEQL / 2) + (l0 >> 1) + lp] = v;
    }
}

// ---- shared middle DIF passes (m=256,64,16), fwd chunk pass (m=4,m=1) ----
__device__ void dif_mid_and_chunk(cf* lds, const cf* __restrict__ tw){
    const int tid = threadIdx.x;
#pragma unroll
    for (int p = 1; p < 4; ++p) {
        const int lm = 10 - 2*p;          // 8,6,4
        const int m  = 1 << lm;
        const int step = 1024 >> lm;
#pragma unroll
        for (int it = 0; it < 4; ++it) {
            int j = tid + (it << 8);
            int k = j & (m-1);
            int g = j >> lm;
            int i0 = (g << (lm+2)) + k;
            cf x0 = lds[phi(i0)];
            cf x1 = lds[phi(i0+m)];
            cf x2 = lds[phi(i0+2*m)];
            cf x3 = lds[phi(i0+3*m)];
            cf b0 = cadd(x0,x2), b1 = csub(x0,x2);
            cf b2 = cadd(x1,x3), b3 = csub(x1,x3);
            cf u0 = cadd(b0,b2);
            cf u2 = csub(b0,b2);
            cf u1 = subi(b1,b3);
            cf u3 = addi(b1,b3);
            int t1 = k*step;
            lds[phi(i0)]     = u0;
            lds[phi(i0+m)]   = cmul(u1, tw[t1]);
            lds[phi(i0+2*m)] = cmul(u2, tw[2*t1]);
            lds[phi(i0+3*m)] = cmul(u3, tw[3*t1]);
        }
        __syncthreads();
    }
    {   // fused m=4 / m=1 register pass; thread owns complexes [16t,16t+16)
        const int b0 = tid << 4;
        const int xr = tid & 15;
        cf v[16];
#pragma unroll
        for (int j=0;j<16;++j) v[j] = lds[b0 + (j ^ xr)];
#pragma unroll
        for (int j=0;j<4;++j){
            cf x0=v[j], x1=v[j+4], x2=v[j+8], x3=v[j+12];
            cf b0v=cadd(x0,x2), b1=csub(x0,x2), b2=cadd(x1,x3), b3=csub(x1,x3);
            cf u0=cadd(b0v,b2), u2=csub(b0v,b2), u1=subi(b1,b3), u3=addi(b1,b3);
            v[j]    = u0;
            v[j+4]  = cmul(u1, W1c(j));
            v[j+8]  = cmul(u2, W2c(j));
            v[j+12] = cmul(u3, W3c(j));
        }
#pragma unroll
        for (int c=0;c<4;++c){
            cf x0=v[4*c], x1=v[4*c+1], x2=v[4*c+2], x3=v[4*c+3];
            cf b0v=cadd(x0,x2), b1=csub(x0,x2), b2=cadd(x1,x3), b3=csub(x1,x3);
            v[4*c]   = cadd(b0v,b2);
            v[4*c+1] = subi(b1,b3);
            v[4*c+2] = csub(b0v,b2);
            v[4*c+3] = addi(b1,b3);
        }
#pragma unroll
        for (int j=0;j<16;++j) lds[b0 + (j ^ xr)] = v[j];
        __syncthreads();
    }
}

// ---- inverse: chunk pass (m=1,m=4) + middle DIT passes (m=16,64,256) ----
__device__ void dit_chunk_and_mid(cf* lds, const cf* __restrict__ tw){
    const int tid = threadIdx.x;
    {
        const int b0 = tid << 4;
        const int xr = tid & 15;
        cf v[16];
#pragma unroll
        for (int j=0;j<16;++j) v[j] = lds[b0 + (j ^ xr)];
#pragma unroll
        for (int c=0;c<4;++c){
            cf a0=v[4*c], a1=v[4*c+1], a2=v[4*c+2], a3=v[4*c+3];
            cf b0v=cadd(a0,a2), b1=csub(a0,a2), b2=cadd(a1,a3), b3=csub(a1,a3);
            v[4*c]   = cadd(b0v,b2);
            v[4*c+1] = addi(b1,b3);
            v[4*c+2] = csub(b0v,b2);
            v[4*c+3] = subi(b1,b3);
        }
#pragma unroll
        for (int j=0;j<4;++j){
            cf a0=v[j];
            cf a1=cmul(v[j+4],  cconjf(W1c(j)));
            cf a2=cmul(v[j+8],  cconjf(W2c(j)));
            cf a3=cmul(v[j+12], cconjf(W3c(j)));
            cf b0v=cadd(a0,a2), b1=csub(a0,a2), b2=cadd(a1,a3), b3=csub(a1,a3);
            v[j]    = cadd(b0v,b2);
            v[j+4]  = addi(b1,b3);
            v[j+8]  = csub(b0v,b2);
            v[j+12] = subi(b1,b3);
        }
#pragma unroll
        for (int j=0;j<16;++j) lds[b0 + (j ^ xr)] = v[j];
        __syncthreads();
    }
#pragma unroll
    for (int p = 0; p < 3; ++p) {
        const int lm = 4 + 2*p;           // 16,64,256
        const int m  = 1 << lm;
        const int step = 1024 >> lm;
#pragma unroll
        for (int it = 0; it < 4; ++it) {
            int j = tid + (it << 8);
            int k = j & (m-1);
            int g = j >> lm;
            int i0 = (g << (lm+2)) + k;
            int t1 = k*step;
            cf a0 = lds[phi(i0)];
            cf a1 = cmul(lds[phi(i0+m)],   cconjf(tw[t1]));
            cf a2 = cmul(lds[phi(i0+2*m)], cconjf(tw[2*t1]));
            cf a3 = cmul(lds[phi(i0+3*m)], cconjf(tw[3*t1]));
            cf b0=cadd(a0,a2), b1=csub(a0,a2), b2=cadd(a1,a3), b3=csub(a1,a3);
            lds[phi(i0)]     = cadd(b0,b2);
            lds[phi(i0+m)]   = addi(b1,b3);
            lds[phi(i0+2*m)] = csub(b0,b2);
            lds[phi(i0+3*m)] = subi(b1,b3);
        }
        __syncthreads();
    }
}

// ---------------- filter row -> packed FFT -> H[d][0..4096] (scaled 1/8192) ----------------
__global__ __launch_bounds__(256) void filt_fft_kernel(
        const float* __restrict__ h, const float* __restrict__ w2,
        const float* __restrict__ b2, const cf* __restrict__ tw4,
        const cf* __restrict__ tw8, cf* __restrict__ kf) {
    __shared__ cf lds[4096];
    const int d = blockIdx.x;
    const int tid = threadIdx.x;
    float wv[16];
#pragma unroll
    for (int j = 0; j < 16; ++j) wv[j] = w2[d * 16 + j];
    const float bb = b2[d];
#pragma unroll
    for (int it = 0; it < 4; ++it) {
        int j = tid + (it << 8);
        const float* h0 = h + (size_t)(2*j) * 16;
        const float* h1 = h + (size_t)(2*(j+1024)) * 16;
        float f0 = bb, f1 = bb, f2 = bb, f3 = bb;
#pragma unroll
        for (int i = 0; i < 16; ++i) {
            f0 += h0[i] * wv[i];  f1 += h0[16+i] * wv[i];
            f2 += h1[i] * wv[i];  f3 += h1[16+i] * wv[i];
        }
        cf x0 = mkc(f0, f1), x1 = mkc(f2, f3);
        cf u0 = cadd(x0,x1);
        cf u2 = csub(x0,x1);
        cf u1 = subi(x0,x1);
        cf u3 = addi(x0,x1);
        lds[phi(j)]      = u0;
        lds[phi(j+1024)] = cmul(u1, tw4[j]);
        lds[phi(j+2048)] = cmul(u2, tw4[2*j]);
        lds[phi(j+3072)] = cmul(u3, tw4[3*j]);
    }
    __syncthreads();
    dif_mid_and_chunk(lds, tw4);
    const float s = 1.f / 8192.f;
    cf* Hrow = kf + (size_t)d * KH;
    const int lane  = tid & 63;
    const int kbase = ((lane & 31) << 6) | ((lane >> 5) << 5) | ((tid >> 6) << 3);
#pragma unroll
    for (int it = 0; it < 8; ++it) {
        int k = kbase + it;
        if (k == 0) {
            cf c0 = lds[0];
            Hrow[0]    = mkc((c0.x + c0.y) * s, 0.f);
            Hrow[4096] = mkc((c0.x - c0.y) * s, 0.f);
            cf c2 = lds[phi(drev(2048))];
            Hrow[2048] = mkc(c2.x * s, -c2.y * s);
        } else {
            int kk = 4096 - k;
            cf ck  = lds[phi(drev(k))];
            cf ckk = lds[phi(drev(kk))];
            cf cc = cconjf(ckk);
            cf E  = (ck + cc) * 0.5f;
            cf Dd = csub(ck, cc);
            cf O  = mkc(Dd.y, -Dd.x) * 0.5f;
            cf wvv = tw8[k];
            cf Xk  = cadd(E, cmul(wvv, O));
            cf wp  = mkc(-wvv.x, wvv.y);
            cf Xkk = cadd(cconjf(E), cmul(wp, cconjf(O)));
            Hrow[k]  = Xk * s;
            Hrow[kk] = Xkk * s;
        }
    }
}

// ---------------- conv: bf16 in -> packed fwd FFT -> multiply -> inv FFT -> bf16 y (in place) ----------------
// grid swizzle: g = (d%8) + 8*b + 32*(d/8)  -> the 4 batch rows sharing H[d] map to the
// same XCD, turning repeat Hrow reads into same-XCD L2 hits.
__global__ __launch_bounds__(256) void conv_kernel(
        unsigned* __restrict__ utyb, const cf* __restrict__ tw4,
        const cf* __restrict__ tw8, const cf* __restrict__ kf) {
    __shared__ cf lds[4096];
    const int g   = blockIdx.x;
    const int d   = (g & 7) | ((g >> 5) << 3);
    const int b   = (g >> 3) & 3;
    const int row = b * DCH + d;
    const int tid = threadIdx.x;
    unsigned* rp = utyb + (size_t)row * (SEQL / 2);
#pragma unroll
    for (int it = 0; it < 4; ++it) {
        int j = tid + (it << 8);
        unsigned q0 = rp[j], q1 = rp[j + 1024];
        cf x0 = mkc(bflo(q0), bfhi(q0));
        cf x1 = mkc(bflo(q1), bfhi(q1));
        cf u0 = cadd(x0,x1);
        cf u2 = csub(x0,x1);
        cf u1 = subi(x0,x1);
        cf u3 = addi(x0,x1);
        lds[phi(j)]      = u0;
        lds[phi(j+1024)] = cmul(u1, tw4[j]);
        lds[phi(j+2048)] = cmul(u2, tw4[2*j]);
        lds[phi(j+3072)] = cmul(u3, tw4[3*j]);
    }
    __syncthreads();
    dif_mid_and_chunk(lds, tw4);
    const cf* Hrow = kf + (size_t)d * KH;
    {
        const int lane  = tid & 63;
        const int kbase = ((lane & 31) << 6) | ((lane >> 5) << 5) | ((tid >> 6) << 3);
#pragma unroll
        for (int it = 0; it < 8; ++it) {
            int k = kbase + it;
            if (k == 0) {
                cf c0 = lds[0];
                float X0 = c0.x + c0.y, X4 = c0.x - c0.y;
                cf H0 = Hrow[0], H4 = Hrow[4096];
                cf Y0 = H0 * X0;
                cf Y4 = H4 * X4;
                cf S  = cadd(Y0, Y4), Dd = csub(Y0, Y4);
                lds[0] = addi(S, Dd);
                int s2 = phi(drev(2048));
                cf c2 = lds[s2];
                cf Y2 = cmul(cconjf(c2), Hrow[2048]);
                lds[s2] = mkc(2.f * Y2.x, -2.f * Y2.y);
            } else {
                int kk = 4096 - k;
                int sk = phi(drev(k)), skk = phi(drev(kk));
                cf ck = lds[sk], ckk = lds[skk];
                cf cc = cconjf(ckk);
                cf E  = (ck + cc) * 0.5f;
                cf Dd = csub(ck, cc);
                cf O  = mkc(Dd.y, -Dd.x) * 0.5f;
                cf wv = tw8[k];
                cf Xk  = cadd(E, cmul(wv, O));
                cf wp  = mkc(-wv.x, wv.y);
                cf Xkk = cadd(cconjf(E), cmul(wp, cconjf(O)));
                cf Yk  = cmul(Xk,  Hrow[k]);
                cf Ykk = cmul(Xkk, Hrow[kk]);
                cf cy = cconjf(Ykk);
                cf S  = cadd(Yk, cy), D2 = csub(Yk, cy);
                cf Zk = addi(S, cmul(cconjf(wv), D2));
                cf cy2 = cconjf(Yk);
                cf S2  = cadd(Ykk, cy2), D3 = csub(Ykk, cy2);
                cf Zkk = subi(S2, cmul(wv, D3));
                lds[sk] = Zk; lds[skk] = Zkk;
            }
        }
    }
    __syncthreads();
    dit_chunk_and_mid(lds, tw4);
#pragma unroll
    for (int it = 0; it < 4; ++it) {
        int j = tid + (it << 8);
        cf a0 = lds[phi(j)];
        cf a1 = cmul(lds[phi(j+1024)], cconjf(tw4[j]));
        cf a2 = cmul(lds[phi(j+2048)], cconjf(tw4[2*j]));
        cf a3 = cmul(lds[phi(j+3072)], cconjf(tw4[3*j]));
        cf b0 = cadd(a0,a2), b1 = csub(a0,a2);
        cf b2 = cadd(a1,a3), b3 = csub(a1,a3);
        cf o0 = cadd(b0,b2);           // n = j
        cf o1 = addi(b1,b3);           // n = j+1024
        rp[j]        = pack2bf(o0.x, o0.y);
        rp[j + 1024] = pack2bf(o1.x, o1.y);
    }
}

typedef __attribute__((ext_vector_type(8))) short short8;
typedef __attribute__((ext_vector_type(4))) float f32x4;

// ---------------- gemm v3: 256x128 tile, BK=64, 3-buffer phase-split pipeline ----------------
__global__ __launch_bounds__(512, 2) void gemm_mfma_v3(
        const unsigned short* __restrict__ ub, const unsigned short* __restrict__ pwb,
        const float* __restrict__ pb, const unsigned short* __restrict__ yb,
        float* __restrict__ out) {
    __shared__ char lds_raw[147456];   // 3 bufs x (A 32K + B 16K); epilogue overlays [128][132] f32
    float (*ysc)[132] = (float(*)[132])lds_raw;

    const int tid  = threadIdx.x;
    const int lane = tid & 63;
    const int wid  = tid >> 6;          // 0..7
    const int wr   = wid >> 1;          // 0..3  (64 m-rows each)
    const int wc   = wid & 1;           // 0..1  (64 n-cols each)
    const int m0   = blockIdx.x * 256;
    const int n0   = blockIdx.y * 128;

    f32x4 acc[4][4] = {};

#pragma unroll
    for (int tt = 0; tt < 2; ++tt) {
#pragma unroll
        for (int un = 0; un < 3; ++un) {
            const unsigned short* gs = (un == 2) ? pwb : ub;
            int growb = (un == 2) ? n0 : (m0 + un * 128);
#pragma unroll
            for (int j = 0; j < 2; ++j) {
                int rr = j * 64 + (tid >> 3);
                int ss = (tid & 7) ^ ((tid >> 3) & 7);
                gload16(gs + (size_t)(growb + rr) * 1024 + tt * 64 + ss * 8,
                        lds_raw + tt * 49152 + un * 16384 + rr * 128 + (tid & 7) * 16);
            }
        }
    }
    asm volatile("s_waitcnt vmcnt(6)" ::: "memory");
    __builtin_amdgcn_sched_barrier(0);
    __builtin_amdgcn_s_barrier();

    for (int t = 0; t < 16; ++t) {
        const int Ab  = (t % 3) * 49152;
        const int Bb  = Ab + 32768;
        const int sbB = ((t + 2) % 3) * 49152;
        const int kt2 = (t + 2) * 64;
#pragma unroll
        for (int q = 0; q < 4; ++q) {
            const int qr = q >> 1, qc = q & 1;
            short8 af[2][2], bfr[2][2];
#pragma unroll
            for (int f = 0; f < 2; ++f) {
                int arow = wr * 64 + qr * 32 + f * 16 + (lane & 15);
                int brow = wc * 64 + qc * 32 + f * 16 + (lane & 15);
#pragma unroll
                for (int kh = 0; kh < 2; ++kh) {
                    int ks = (lane >> 4) + 4 * kh;
                    af[f][kh]  = *(short8*)(lds_raw + Ab + arow * 128 + (ks ^ (arow & 7)) * 16);
                    bfr[f][kh] = *(short8*)(lds_raw + Bb + brow * 128 + (ks ^ (brow & 7)) * 16);
                }
            }
            if (q < 3 && t < 14) {
                const unsigned short* gs = (q == 2) ? pwb : ub;
                int growb = (q == 2) ? n0 : (m0 + q * 128);
#pragma unroll
                for (int j = 0; j < 2; ++j) {
                    int rr = j * 64 + (tid >> 3);
                    int ss = (tid & 7) ^ ((tid >> 3) & 7);
                    gload16(gs + (size_t)(growb + rr) * 1024 + kt2 + ss * 8,
                            lds_raw + sbB + q * 16384 + rr * 128 + (tid & 7) * 16);
                }
            }
            __builtin_amdgcn_s_barrier();
            asm volatile("s_waitcnt lgkmcnt(0)" ::: "memory");
            __builtin_amdgcn_sched_barrier(0);
            __builtin_amdgcn_s_setprio(1);
#pragma unroll
            for (int fa = 0; fa < 2; ++fa)
#pragma unroll
                for (int fb = 0; fb < 2; ++fb)
#pragma unroll
                    for (int kh = 0; kh < 2; ++kh)
                        acc[qr * 2 + fa][qc * 2 + fb] = __builtin_amdgcn_mfma_f32_16x16x32_bf16(
                            af[fa][kh], bfr[fb][kh], acc[qr * 2 + fa][qc * 2 + fb], 0, 0, 0);
            __builtin_amdgcn_s_setprio(0);
            if (q == 3) {
                if (t < 14)       asm volatile("s_waitcnt vmcnt(6)" ::: "memory");
                else if (t == 14) asm volatile("s_waitcnt vmcnt(0)" ::: "memory");
                __builtin_amdgcn_sched_barrier(0);
            }
            __builtin_amdgcn_s_barrier();
        }
    }

    __syncthreads();
    const int b  = m0 >> 12;
    const int l0 = m0 & (SEQL - 1);
    float pbv[4];
#pragma unroll
    for (int nf = 0; nf < 4; ++nf)
        pbv[nf] = pb[n0 + wc * 64 + nf * 16 + (lane & 15)];

    for (int c = 0; c < 2; ++c) {
        __syncthreads();
        {
            int dn = tid >> 2;
            int lq = tid & 3;
            const uint4* uptr = (const uint4*)(yb + (((size_t)(b * DCH + n0 + dn)) << 12) + l0 + c * 128);
#pragma unroll
            for (int jj = 0; jj < 4; ++jj) {
                uint4 w4 = uptr[lq * 4 + jj];
                int lb = (lq * 4 + jj) * 8;
                ysc[lb+0][dn] = bflo(w4.x); ysc[lb+1][dn] = bfhi(w4.x);
                ysc[lb+2][dn] = bflo(w4.y); ysc[lb+3][dn] = bfhi(w4.y);
                ysc[lb+4][dn] = bflo(w4.z); ysc[lb+5][dn] = bfhi(w4.z);
                ysc[lb+6][dn] = bflo(w4.w); ysc[lb+7][dn] = bfhi(w4.w);
            }
        }
        __syncthreads();
        if ((wr >> 1) == c) {
#pragma unroll
            for (int mf = 0; mf < 4; ++mf)
#pragma unroll
                for (int i = 0; i < 4; ++i) {
                    int lrow = (wr & 1) * 64 + mf * 16 + (lane >> 4) * 4 + i;
                    int m = m0 + c * 128 + lrow;
#pragma unroll
                    for (int nf = 0; nf < 4; ++nf) {
                        int nl = wc * 64 + nf * 16 + (lane & 15);
                        int n = n0 + nl;
                        float proj = acc[mf][nf][i] + pbv[nf];
                        float ures = __uint_as_float((unsigned)ub[(size_t)m * DCH + n] << 16);
                        out[(size_t)m * DCH + n] = ysc[lrow][nl] * proj + ures;
                    }
                }
        }
    }
}

// ---------------- gemm fallback (reg-staged): used when ws too small ----------------
__global__ __launch_bounds__(256, 3) void gemm_mfma_fb(
        const float* __restrict__ u, const float* __restrict__ pw,
        const float* __restrict__ pb, const unsigned short* __restrict__ yb,
        float* __restrict__ out) {
    __shared__ char lds_raw[34816];
    float (*ysc)[132] = (float(*)[132])lds_raw;
    const int tid  = threadIdx.x;
    const int lane = tid & 63;
    const int wid  = tid >> 6;
    const int wr   = wid >> 1;
    const int wc   = wid & 1;
    const int m0   = blockIdx.x * 128;
    const int n0   = blockIdx.y * 128;
    f32x4 acc[4][4] = {};
    float4 ra[4], rb[4];
    int s_row[4], s_f4[4];
#pragma unroll
    for (int j = 0; j < 4; ++j) {
        int idx = j * 256 + tid;
        s_row[j] = idx >> 3;
        s_f4[j]  = idx & 7;
    }
#define LOADT(kt)                                                                     \
    {                                                                                 \
        _Pragma("unroll")                                                             \
        for (int j = 0; j < 4; ++j) {                                                 \
            ra[j] = *(const float4*)&u [(size_t)(m0 + s_row[j]) * DCH + (kt) + s_f4[j] * 4]; \
            rb[j] = *(const float4*)&pw[(size_t)(n0 + s_row[j]) * DCH + (kt) + s_f4[j] * 4]; \
        }                                                                             \
    }
#define WRITET(base)                                                                  \
    {                                                                                 \
        _Pragma("unroll")                                                             \
        for (int j = 0; j < 4; ++j) {                                                 \
            int off = (base) + ((s_row[j] * 64 + s_f4[j] * 8) ^ ((s_row[j] & 3) << 4)); \
            uint2 pa, pbv2;                                                           \
            pa.x   = pack2bf(ra[j].x, ra[j].y);  pa.y   = pack2bf(ra[j].z, ra[j].w);  \
            pbv2.x = pack2bf(rb[j].x, rb[j].y);  pbv2.y = pack2bf(rb[j].z, rb[j].w);  \
            *(uint2*)(lds_raw + off)        = pa;                                     \
            *(uint2*)(lds_raw + off + 8192) = pbv2;                                   \
        }                                                                             \
    }
    LOADT(0);
    WRITET(0);
    LOADT(32);
    __syncthreads();
    for (int t = 0; t < 32; ++t) {
        const int cur = (t & 1) << 14;
        short8 af[4], bfr[4];
#pragma unroll
        for (int f = 0; f < 4; ++f) {
            int rowA = wr * 64 + f * 16 + (lane & 15);
            int rowB = wc * 64 + f * 16 + (lane & 15);
            int offA = cur + ((rowA * 64 + ((lane >> 4) * 16)) ^ ((rowA & 3) << 4));
            int offB = cur + 8192 + ((rowB * 64 + ((lane >> 4) * 16)) ^ ((rowB & 3) << 4));
            af[f]  = *(short8*)(lds_raw + offA);
            bfr[f] = *(short8*)(lds_raw + offB);
        }
        if (t < 31) WRITET(cur ^ 16384);
        if (t < 30) LOADT((t + 2) * 32);
#pragma unroll
        for (int mf = 0; mf < 4; ++mf)
#pragma unroll
            for (int nf = 0; nf < 4; ++nf)
                acc[mf][nf] = __builtin_amdgcn_mfma_f32_16x16x32_bf16(
                    af[mf], bfr[nf], acc[mf][nf], 0, 0, 0);
        __syncthreads();
    }
    const int b  = m0 >> 12;
    const int l0 = m0 & (SEQL - 1);
    float pbv[4];
#pragma unroll
    for (int nf = 0; nf < 4; ++nf)
        pbv[nf] = pb[n0 + wc * 64 + nf * 16 + (lane & 15)];
    for (int c = 0; c < 2; ++c) {
        __syncthreads();
#pragma unroll
        for (int j = 0; j < 4; ++j) {
            int idx = j * 256 + tid;
            int dn  = idx >> 3;
            int lg  = idx & 7;
            uint4 w4 = *(const uint4*)&yb[(((size_t)(b * DCH + n0 + dn)) << 12) + l0 + c * 64 + lg * 8];
            int lb = lg * 8;
            ysc[lb+0][dn] = bflo(w4.x); ysc[lb+1][dn] = bfhi(w4.x);
            ysc[lb+2][dn] = bflo(w4.y); ysc[lb+3][dn] = bfhi(w4.y);
            ysc[lb+4][dn] = bflo(w4.z); ysc[lb+5][dn] = bfhi(w4.z);
            ysc[lb+6][dn] = bflo(w4.w); ysc[lb+7][dn] = bfhi(w4.w);
        }
        __syncthreads();
        if (wr == c) {
#pragma unroll
            for (int mf = 0; mf < 4; ++mf)
#pragma unroll
                for (int i = 0; i < 4; ++i) {
                    int lrow = mf * 16 + (lane >> 4) * 4 + i;
                    int m = m0 + c * 64 + lrow;
#pragma unroll
                    for (int nf = 0; nf < 4; ++nf) {
                        int nl = wc * 64 + nf * 16 + (lane & 15);
                        int n = n0 + nl;
                        float proj = acc[mf][nf][i] + pbv[nf];
                        out[(size_t)m * DCH + n] = ysc[lrow][nl] * proj + u[(size_t)m * DCH + n];
                    }
                }
        }
    }
#undef LOADT
#undef WRITET
}

extern "C" void kernel_launch(void* const* d_in, const int* in_sizes, int n_in,
                              void* d_out, int out_size, void* d_ws, size_t ws_size,
                              hipStream_t stream) {
    const float* u  = (const float*)d_in[0];
    const float* z  = (const float*)d_in[1];
    const float* w1 = (const float*)d_in[2];
    const float* b1 = (const float*)d_in[3];
    const float* w2 = (const float*)d_in[4];
    const float* b2 = (const float*)d_in[5];
    const float* pw = (const float*)d_in[6];
    const float* pb = (const float*)d_in[7];
    float* out = (float*)d_out;

    float*    h    = (float*)d_ws;                        // 256 KB
    unsigned* utyb = (unsigned*)((char*)d_ws + 262144);   // 32 MB (bf16-pair rows; y bf16 in place)
    cf* kf = (cf*)d_out;                                  // 33.5 MB scratch (overwritten by gemm)

    const size_t ub_off  = 262144 + (size_t)BATCH * DCH * (SEQL / 2) * sizeof(unsigned);
    const size_t pwb_off = ub_off + (size_t)BATCH * SEQL * DCH * sizeof(unsigned short);
    const size_t tw_off  = pwb_off + (size_t)DCH * DCH * sizeof(unsigned short);
    const size_t need    = tw_off + 2 * 4096 * sizeof(cf);
    const bool   big     = ws_size >= need;

    cf* tw4 = big ? (cf*)((char*)d_ws + tw_off) : (cf*)((char*)d_out + (40u << 20));
    cf* tw8 = tw4 + 4096;
    unsigned short* ub  = big ? (unsigned short*)((char*)d_ws + ub_off)  : (unsigned short*)0;
    unsigned short* pwb = big ? (unsigned short*)((char*)d_ws + pwb_off) : (unsigned short*)0;

    prep_kernel<<<dim3(big ? 544 : 32), dim3(256), 0, stream>>>(tw4, tw8, z, w1, b1, h, pw, pwb);
    transpose_kernel<<<dim3(SEQL / 32, DCH / 32, BATCH), dim3(32, 8), 0, stream>>>(u, utyb, ub);
    filt_fft_kernel<<<dim3(DCH), dim3(256), 0, stream>>>(h, w2, b2, tw4, tw8, kf);
    conv_kernel<<<dim3(BATCH * DCH), dim3(256), 0, stream>>>(utyb, tw4, tw8, kf);
    if (big)
        gemm_mfma_v3<<<dim3(64, 8), dim3(512), 0, stream>>>(ub, pwb, pb, (const unsigned short*)utyb, out);
    else
        gemm_mfma_fb<<<dim3(128, 8), dim3(256), 0, stream>>>(u, pw, pb, (const unsigned short*)utyb, out);
}